// Round 5
// baseline (153.580 us; speedup 1.0000x reference)
//
#include <hip/hip_runtime.h>

typedef short bf16x8 __attribute__((ext_vector_type(8)));
typedef float f32x4 __attribute__((ext_vector_type(4)));

static __device__ __forceinline__ unsigned short f2bf(float f) {
  unsigned u = __builtin_bit_cast(unsigned, f);
  u += 0x7FFFu + ((u >> 16) & 1u);   // round-nearest-even to bf16
  return (unsigned short)(u >> 16);
}

static __device__ __forceinline__ bf16x8 pack8(const float* p) {
  float4 a = *(const float4*)p;
  float4 b = *(const float4*)(p + 4);
  bf16x8 r;
  r[0] = (short)f2bf(a.x); r[1] = (short)f2bf(a.y);
  r[2] = (short)f2bf(a.z); r[3] = (short)f2bf(a.w);
  r[4] = (short)f2bf(b.x); r[5] = (short)f2bf(b.y);
  r[6] = (short)f2bf(b.z); r[7] = (short)f2bf(b.w);
  return r;
}

// ---------------- LayerNorm: x[B,C,H,W] f32 -> xn[B,H,W,C] bf16 ----------------
__global__ __launch_bounds__(256) void ln_kernel(
    const float* __restrict__ x, const float* __restrict__ lg,
    const float* __restrict__ lb, unsigned short* __restrict__ xn) {
  __shared__ float tile[128][65];
  __shared__ float ps[8][64];
  __shared__ float mu_s[64], rs_s[64];
  const int bid = blockIdx.x;
  const int b = bid >> 6, h = bid & 63;
  const int tid = threadIdx.x;
  const int w = tid & 63, cq = tid >> 6;
  const float* xp = x + ((size_t)(b * 128) * 64 + h) * 64 + w;
  float s1 = 0.f, s2 = 0.f;
#pragma unroll
  for (int c = cq; c < 128; c += 4) {
    float v = xp[(size_t)c * 4096];
    tile[c][w] = v;
    s1 += v; s2 += v * v;
  }
  ps[cq][w] = s1; ps[4 + cq][w] = s2;
  __syncthreads();
  if (tid < 64) {
    float a1 = ps[0][tid] + ps[1][tid] + ps[2][tid] + ps[3][tid];
    float a2 = ps[4][tid] + ps[5][tid] + ps[6][tid] + ps[7][tid];
    float mu = a1 * 0.0078125f;
    float var = a2 * 0.0078125f - mu * mu;
    mu_s[tid] = mu;
    rs_s[tid] = rsqrtf(var + 1e-5f);
  }
  __syncthreads();
  const int lane = tid & 63, w4 = tid >> 6;
  const int c0 = lane * 2;
  const float g0 = lg[c0], g1 = lg[c0 + 1], b0 = lb[c0], b1 = lb[c0 + 1];
#pragma unroll
  for (int w2 = w4; w2 < 64; w2 += 4) {
    const float mu = mu_s[w2], rs = rs_s[w2];
    float y0 = (tile[c0][w2] - mu) * rs * g0 + b0;
    float y1 = (tile[c0 + 1][w2] - mu) * rs * g1 + b1;
    unsigned pk = (unsigned)f2bf(y0) | ((unsigned)f2bf(y1) << 16);
    *(unsigned*)((unsigned char*)xn + ((size_t)((b * 64 + h) * 64 + w2)) * 256 + c0 * 2) = pk;
  }
}

// ---------------- Persistent bidirectional GRU scan ----------------
// grid = 4 dirs * 64 groups; block = 512 (8 waves); 16 sequences per block.
// W is the MFMA A operand, x/h tile is B; D[m=gatecol][n=seq].
// x B-fragments loaded DIRECTLY from global into registers, prefetch depth 2.
// x-gate MFMAs for step t+1 ping-pong (static phase macro — no runtime
// indexing into register arrays, rule #20). h in LDS with full 4-bit XOR
// swizzle (conflict-free b128). One raw lgkmcnt-only barrier per step.
__global__ __launch_bounds__(512, 1) void scan_kernel(
    const unsigned short* __restrict__ xn, unsigned short* __restrict__ cat,
    const float* __restrict__ wih0, const float* __restrict__ whh0,
    const float* __restrict__ bih0, const float* __restrict__ bhh0,
    const float* __restrict__ wih1, const float* __restrict__ whh1,
    const float* __restrict__ bih1, const float* __restrict__ bhh1,
    const float* __restrict__ wih2, const float* __restrict__ whh2,
    const float* __restrict__ bih2, const float* __restrict__ bhh2,
    const float* __restrict__ wih3, const float* __restrict__ whh3,
    const float* __restrict__ bih3, const float* __restrict__ bhh3) {
  __shared__ __align__(16) unsigned char lds[8192];
  const int tid = threadIdx.x;
  const int bid = blockIdx.x;
  const int dir = bid >> 6;
  const int grp = bid & 63;
  const int fwd = !(dir & 1);
  const int vert = dir >> 1;
  const int b = grp >> 2;
  const int r0 = (grp & 3) << 4;
  const int wv = tid >> 6;
  const int lane = tid & 63;
  const int l15 = lane & 15;
  const int l4 = lane >> 4;

  const float* wih = dir == 0 ? wih0 : dir == 1 ? wih1 : dir == 2 ? wih2 : wih3;
  const float* whh = dir == 0 ? whh0 : dir == 1 ? whh1 : dir == 2 ? whh2 : whh3;
  const float* bih = dir == 0 ? bih0 : dir == 1 ? bih1 : dir == 2 ? bih2 : bih3;
  const float* bhh = dir == 0 ? bhh0 : dir == 1 ? bhh1 : dir == 2 ? bhh2 : bhh3;

  // A-fragments (weights) in VGPRs: lane's m-row = gatecol wv*16 + l15,
  // k = kc*32 + l4*8 + 0..7.
  const int ca = (wv << 4) + l15;
  bf16x8 wf[3][2][4];
#pragma unroll
  for (int g = 0; g < 3; ++g) {
#pragma unroll
    for (int s = 0; s < 2; ++s) {
      const float* Wp = s ? whh : wih;
#pragma unroll
      for (int kc = 0; kc < 4; ++kc)
        wf[g][s][kc] = pack8(Wp + (size_t)((g << 7) + ca) * 128 + (kc << 5) + (l4 << 3));
    }
  }
  // Biases: 4 consecutive channels per lane (c = wv*16 + l4*4 + 0..3).
  const int cb = (wv << 4) + (l4 << 2);
  f32x4 br4, bz4, bnx4, bnh4;
  {
    float4 a = *(const float4*)(bih + cb), b2 = *(const float4*)(bhh + cb);
    br4[0] = a.x + b2.x; br4[1] = a.y + b2.y; br4[2] = a.z + b2.z; br4[3] = a.w + b2.w;
    a = *(const float4*)(bih + 128 + cb); b2 = *(const float4*)(bhh + 128 + cb);
    bz4[0] = a.x + b2.x; bz4[1] = a.y + b2.y; bz4[2] = a.z + b2.z; bz4[3] = a.w + b2.w;
    a = *(const float4*)(bih + 256 + cb);
    bnx4[0] = a.x; bnx4[1] = a.y; bnx4[2] = a.z; bnx4[3] = a.w;
    b2 = *(const float4*)(bhh + 256 + cb);
    bnh4[0] = b2.x; bnh4[1] = b2.y; bnh4[2] = b2.z; bnh4[3] = b2.w;
  }

  // Per-lane global x pointer (B-fragment rows): seq row = r0 + l15.
  const int seq = r0 + l15;
  const unsigned char* xlp =
      (const unsigned char*)xn +
      (vert ? ((size_t)b << 20) + (size_t)seq * 256 + (l4 << 4)
            : ((size_t)(b * 64 + seq) << 14) + (l4 << 4));
  const int xstep = vert ? 16384 : 256;
  // Per-lane cat store pointer.
  unsigned char* catp =
      (unsigned char*)cat +
      ((size_t)b * 4096 + (size_t)(vert ? seq : seq * 64)) * 1024 + dir * 256 + (cb << 1);
  const int cstep = vert ? 65536 : 1024;

  // zero hbuf0 (@0, 4KB)
  *(unsigned long long*)(lds + tid * 8) = 0ull;
  f32x4 hst = {0.f, 0.f, 0.f, 0.f};

  // Prologue: load x[t(0)], x[t(1)]; compute x-gates for step 0.
  bf16x8 xaq0[4], xaq1[4];
  {
    const int ta = (fwd ? 0 : 63) * xstep, tb = (fwd ? 1 : 62) * xstep;
#pragma unroll
    for (int kc = 0; kc < 4; ++kc) {
      xaq0[kc] = *(const bf16x8*)(xlp + ta + (kc << 6));
      xaq1[kc] = *(const bf16x8*)(xlp + tb + (kc << 6));
    }
  }
  f32x4 gr0, gz0, gnx0, gr1, gz1, gnx1;
  gr0 = br4; gz0 = bz4; gnx0 = bnx4;
#pragma unroll
  for (int kc = 0; kc < 4; ++kc) {
    gr0 = __builtin_amdgcn_mfma_f32_16x16x32_bf16(wf[0][0][kc], xaq0[kc], gr0, 0, 0, 0);
    gz0 = __builtin_amdgcn_mfma_f32_16x16x32_bf16(wf[1][0][kc], xaq0[kc], gz0, 0, 0, 0);
    gnx0 = __builtin_amdgcn_mfma_f32_16x16x32_bf16(wf[2][0][kc], xaq0[kc], gnx0, 0, 0, 0);
  }
  __syncthreads();  // hbuf0 zero visible

  // One scan step; all register-array indices are compile-time constants.
  // CUR phase uses xaqC (x[t]), gC accumulators; prefetches x[t+2] into xaqC;
  // computes next step's x-gates into gN from xaqN; h via hbuf[CUR]->hbuf[NXT].
#define STEP(TT, CURO, NXTO, xaqC, xaqN, grC, gzC, gnxC, grN, gzN, gnxN)        \
  {                                                                             \
    const int t = fwd ? (TT) : 63 - (TT);                                       \
    const int tl = (TT) + 2 > 63 ? 63 : (TT) + 2;                               \
    const int tld = (fwd ? tl : 63 - tl) * xstep;                               \
    _Pragma("unroll")                                                           \
    for (int kc = 0; kc < 4; ++kc)                                              \
      xaqC[kc] = *(const bf16x8*)(xlp + tld + (kc << 6));                       \
    bf16x8 ha[4];                                                               \
    _Pragma("unroll")                                                           \
    for (int kc = 0; kc < 4; ++kc) {                                            \
      const int base = (l15 * 256 + (kc << 6) + (l4 << 4)) ^ (l15 << 4);        \
      ha[kc] = *(const bf16x8*)(lds + (CURO) + base);                           \
    }                                                                           \
    grN = br4; gzN = bz4; gnxN = bnx4;                                          \
    _Pragma("unroll")                                                           \
    for (int kc = 0; kc < 4; ++kc) {                                            \
      grN = __builtin_amdgcn_mfma_f32_16x16x32_bf16(wf[0][0][kc], xaqN[kc], grN, 0, 0, 0);  \
      gzN = __builtin_amdgcn_mfma_f32_16x16x32_bf16(wf[1][0][kc], xaqN[kc], gzN, 0, 0, 0);  \
      gnxN = __builtin_amdgcn_mfma_f32_16x16x32_bf16(wf[2][0][kc], xaqN[kc], gnxN, 0, 0, 0);\
    }                                                                           \
    f32x4 ar = grC, az = gzC, anh = bnh4;                                       \
    _Pragma("unroll")                                                           \
    for (int kc = 0; kc < 4; ++kc) {                                            \
      ar = __builtin_amdgcn_mfma_f32_16x16x32_bf16(wf[0][1][kc], ha[kc], ar, 0, 0, 0);      \
      az = __builtin_amdgcn_mfma_f32_16x16x32_bf16(wf[1][1][kc], ha[kc], az, 0, 0, 0);      \
      anh = __builtin_amdgcn_mfma_f32_16x16x32_bf16(wf[2][1][kc], ha[kc], anh, 0, 0, 0);    \
    }                                                                           \
    f32x4 hnew;                                                                 \
    _Pragma("unroll")                                                           \
    for (int r = 0; r < 4; ++r) {                                               \
      const float rr = __builtin_amdgcn_rcpf(1.f + __expf(-ar[r]));             \
      const float zz = __builtin_amdgcn_rcpf(1.f + __expf(-az[r]));             \
      const float pre = gnxC[r] + rr * anh[r];                                  \
      const float e2 = __expf(-2.f * pre);                                      \
      const float nn = fmaf(2.f, __builtin_amdgcn_rcpf(1.f + e2), -1.f);        \
      hnew[r] = nn + zz * (hst[r] - nn);                                        \
    }                                                                           \
    hst = hnew;                                                                 \
    const unsigned hp0 = (unsigned)f2bf(hnew[0]) | ((unsigned)f2bf(hnew[1]) << 16); \
    const unsigned hp1 = (unsigned)f2bf(hnew[2]) | ((unsigned)f2bf(hnew[3]) << 16); \
    {                                                                           \
      unsigned long long hp = (unsigned long long)hp0 | ((unsigned long long)hp1 << 32); \
      *(unsigned long long*)(lds + (NXTO) + ((l15 * 256 + (cb << 1)) ^ (l15 << 4))) = hp; \
    }                                                                           \
    {                                                                           \
      uint2 v; v.x = hp0; v.y = hp1;                                            \
      *(uint2*)(catp + t * cstep) = v;                                          \
    }                                                                           \
    asm volatile("s_waitcnt lgkmcnt(0)" ::: "memory");                          \
    __builtin_amdgcn_s_barrier();                                               \
    asm volatile("" ::: "memory");                                              \
  }

  for (int tt2 = 0; tt2 < 64; tt2 += 2) {
    STEP(tt2, 0, 4096, xaq0, xaq1, gr0, gz0, gnx0, gr1, gz1, gnx1);
    STEP(tt2 + 1, 4096, 0, xaq1, xaq0, gr1, gz1, gnx1, gr0, gz0, gnx0);
  }
#undef STEP
}

// ---------------- Projection: out = cat[65536,512] @ pw^T + pb + x, -> [B,C,HW] ----------------
__global__ __launch_bounds__(256, 2) void proj_kernel(
    const unsigned short* __restrict__ cat, const float* __restrict__ pw,
    const float* __restrict__ pb, const float* __restrict__ x,
    float* __restrict__ out) {
  __shared__ __align__(16) unsigned char at[65536];
  const int tid = threadIdx.x;
  const int bid = blockIdx.x;
  const int row0 = bid << 6;
  const int b = row0 >> 12;
  const int hw0 = row0 & 4095;
  const int wv = tid >> 6, lane = tid & 63, l15 = lane & 15, l4 = lane >> 4;

#pragma unroll
  for (int it = 0; it < 16; ++it) {
    const int item = tid + (it << 8);
    const int rr = item >> 6, ckk = item & 63;
    uint4 v = *(const uint4*)((const unsigned char*)cat +
                              ((size_t)(row0 + rr)) * 1024 + ckk * 16);
    *(uint4*)(at + rr * 1024 + ((ckk ^ (rr & 7)) << 4)) = v;
  }

  bf16x8 wfr[2][16];
  float pbv[2];
#pragma unroll
  for (int ct = 0; ct < 2; ++ct) {
    const int cc = (wv << 5) + (ct << 4) + l15;
    pbv[ct] = pb[cc];
#pragma unroll
    for (int kc = 0; kc < 16; ++kc)
      wfr[ct][kc] = pack8(pw + (size_t)cc * 512 + (kc << 5) + (l4 << 3));
  }
  __syncthreads();

  f32x4 acc[4][2];
#pragma unroll
  for (int mt = 0; mt < 4; ++mt) {
    acc[mt][0] = {pbv[0], pbv[0], pbv[0], pbv[0]};
    acc[mt][1] = {pbv[1], pbv[1], pbv[1], pbv[1]};
  }
#pragma unroll
  for (int mt = 0; mt < 4; ++mt) {
    const int rr = (mt << 4) + l15;
#pragma unroll
    for (int kc = 0; kc < 16; ++kc) {
      bf16x8 af =
          *(const bf16x8*)(at + rr * 1024 + ((((kc << 2) + l4) ^ (rr & 7)) << 4));
      acc[mt][0] = __builtin_amdgcn_mfma_f32_16x16x32_bf16(af, wfr[0][kc], acc[mt][0], 0, 0, 0);
      acc[mt][1] = __builtin_amdgcn_mfma_f32_16x16x32_bf16(af, wfr[1][kc], acc[mt][1], 0, 0, 0);
    }
  }

#pragma unroll
  for (int mt = 0; mt < 4; ++mt) {
#pragma unroll
    for (int ct = 0; ct < 2; ++ct) {
      const int cc = (wv << 5) + (ct << 4) + l15;
      const int hwb = hw0 + (mt << 4) + (l4 << 2);
      const size_t off = (size_t)(b * 128 + cc) * 4096 + hwb;
      float4 xv = *(const float4*)(x + off);
      float4 o;
      o.x = acc[mt][ct][0] + xv.x;
      o.y = acc[mt][ct][1] + xv.y;
      o.z = acc[mt][ct][2] + xv.z;
      o.w = acc[mt][ct][3] + xv.w;
      *(float4*)(out + off) = o;
    }
  }
}

extern "C" void kernel_launch(void* const* d_in, const int* in_sizes, int n_in,
                              void* d_out, int out_size, void* d_ws, size_t ws_size,
                              hipStream_t stream) {
  const float* x = (const float*)d_in[0];
  const float* lg = (const float*)d_in[1];
  const float* lb = (const float*)d_in[2];
  unsigned short* xn = (unsigned short*)d_ws;  // [16][64][64][128] bf16 = 16.8MB
  unsigned short* cat =
      (unsigned short*)((unsigned char*)d_ws + (size_t)16 * 64 * 64 * 128 * 2);  // [65536][512] bf16 = 67MB

  ln_kernel<<<1024, 256, 0, stream>>>(x, lg, lb, xn);
  scan_kernel<<<256, 512, 0, stream>>>(
      xn, cat,
      (const float*)d_in[3], (const float*)d_in[4], (const float*)d_in[5], (const float*)d_in[6],
      (const float*)d_in[7], (const float*)d_in[8], (const float*)d_in[9], (const float*)d_in[10],
      (const float*)d_in[11], (const float*)d_in[12], (const float*)d_in[13], (const float*)d_in[14],
      (const float*)d_in[15], (const float*)d_in[16], (const float*)d_in[17], (const float*)d_in[18]);
  proj_kernel<<<1024, 256, 0, stream>>>(cat, (const float*)d_in[19], (const float*)d_in[20], x,
                                        (float*)d_out);
}

// Round 6
// 140.302 us; speedup vs baseline: 1.0946x; 1.0946x over previous
//
#include <hip/hip_runtime.h>

typedef short bf16x8 __attribute__((ext_vector_type(8)));
typedef float f32x4 __attribute__((ext_vector_type(4)));

static __device__ __forceinline__ unsigned short f2bf(float f) {
  unsigned u = __builtin_bit_cast(unsigned, f);
  u += 0x7FFFu + ((u >> 16) & 1u);   // round-nearest-even to bf16
  return (unsigned short)(u >> 16);
}

static __device__ __forceinline__ bf16x8 pack8(const float* p) {
  float4 a = *(const float4*)p;
  float4 b = *(const float4*)(p + 4);
  bf16x8 r;
  r[0] = (short)f2bf(a.x); r[1] = (short)f2bf(a.y);
  r[2] = (short)f2bf(a.z); r[3] = (short)f2bf(a.w);
  r[4] = (short)f2bf(b.x); r[5] = (short)f2bf(b.y);
  r[6] = (short)f2bf(b.z); r[7] = (short)f2bf(b.w);
  return r;
}

// ---------------- LayerNorm: x[B,C,H,W] f32 -> xn[B,H,W,C] bf16 ----------------
__global__ __launch_bounds__(256) void ln_kernel(
    const float* __restrict__ x, const float* __restrict__ lg,
    const float* __restrict__ lb, unsigned short* __restrict__ xn) {
  __shared__ float tile[128][65];
  __shared__ float ps[8][64];
  __shared__ float mu_s[64], rs_s[64];
  const int bid = blockIdx.x;
  const int b = bid >> 6, h = bid & 63;
  const int tid = threadIdx.x;
  const int w = tid & 63, cq = tid >> 6;
  const float* xp = x + ((size_t)(b * 128) * 64 + h) * 64 + w;
  float s1 = 0.f, s2 = 0.f;
#pragma unroll
  for (int c = cq; c < 128; c += 4) {
    float v = xp[(size_t)c * 4096];
    tile[c][w] = v;
    s1 += v; s2 += v * v;
  }
  ps[cq][w] = s1; ps[4 + cq][w] = s2;
  __syncthreads();
  if (tid < 64) {
    float a1 = ps[0][tid] + ps[1][tid] + ps[2][tid] + ps[3][tid];
    float a2 = ps[4][tid] + ps[5][tid] + ps[6][tid] + ps[7][tid];
    float mu = a1 * 0.0078125f;
    float var = a2 * 0.0078125f - mu * mu;
    mu_s[tid] = mu;
    rs_s[tid] = rsqrtf(var + 1e-5f);
  }
  __syncthreads();
  const int lane = tid & 63, w4 = tid >> 6;
  const int c0 = lane * 2;
  const float g0 = lg[c0], g1 = lg[c0 + 1], b0 = lb[c0], b1 = lb[c0 + 1];
#pragma unroll
  for (int w2 = w4; w2 < 64; w2 += 4) {
    const float mu = mu_s[w2], rs = rs_s[w2];
    float y0 = (tile[c0][w2] - mu) * rs * g0 + b0;
    float y1 = (tile[c0 + 1][w2] - mu) * rs * g1 + b1;
    unsigned pk = (unsigned)f2bf(y0) | ((unsigned)f2bf(y1) << 16);
    *(unsigned*)((unsigned char*)xn + ((size_t)((b * 64 + h) * 64 + w2)) * 256 + c0 * 2) = pk;
  }
}

// ---------------- Persistent bidirectional GRU scan ----------------
// grid = 4 dirs * 64 groups; block = 512 (8 waves); 16 sequences per block.
// W is the MFMA A operand, x/h tile is B; D[m=gatecol][n=seq].
// x staged in LDS (coalesced, shared by all 8 waves); staging register is
// ping-ponged ACROSS the barrier so the ds_write never waits on vmcnt.
// x-chains and h-chains use separate accumulators (depth-4, 6-way ILP).
// Full-row XOR swizzle (row<<4) on both buffers: conflict-free b128.
// One raw lgkmcnt-only barrier per step.
__global__ __launch_bounds__(512, 2) void scan_kernel(
    const unsigned short* __restrict__ xn, unsigned short* __restrict__ cat,
    const float* __restrict__ wih0, const float* __restrict__ whh0,
    const float* __restrict__ bih0, const float* __restrict__ bhh0,
    const float* __restrict__ wih1, const float* __restrict__ whh1,
    const float* __restrict__ bih1, const float* __restrict__ bhh1,
    const float* __restrict__ wih2, const float* __restrict__ whh2,
    const float* __restrict__ bih2, const float* __restrict__ bhh2,
    const float* __restrict__ wih3, const float* __restrict__ whh3,
    const float* __restrict__ bih3, const float* __restrict__ bhh3) {
  __shared__ __align__(16) unsigned char lds[16384];
  const int tid = threadIdx.x;
  const int bid = blockIdx.x;
  const int dir = bid >> 6;
  const int grp = bid & 63;
  const int fwd = !(dir & 1);
  const int vert = dir >> 1;
  const int b = grp >> 2;
  const int r0 = (grp & 3) << 4;
  const int wv = tid >> 6;
  const int lane = tid & 63;
  const int l15 = lane & 15;
  const int l4 = lane >> 4;

  const float* wih = dir == 0 ? wih0 : dir == 1 ? wih1 : dir == 2 ? wih2 : wih3;
  const float* whh = dir == 0 ? whh0 : dir == 1 ? whh1 : dir == 2 ? whh2 : whh3;
  const float* bih = dir == 0 ? bih0 : dir == 1 ? bih1 : dir == 2 ? bih2 : bih3;
  const float* bhh = dir == 0 ? bhh0 : dir == 1 ? bhh1 : dir == 2 ? bhh2 : bhh3;

  // A-fragments (weights) in VGPRs/AGPRs: lane's m-row = gatecol wv*16 + l15,
  // k = kc*32 + l4*8 + 0..7.
  const int ca = (wv << 4) + l15;
  bf16x8 wf[3][2][4];
#pragma unroll
  for (int g = 0; g < 3; ++g) {
#pragma unroll
    for (int s = 0; s < 2; ++s) {
      const float* Wp = s ? whh : wih;
#pragma unroll
      for (int kc = 0; kc < 4; ++kc)
        wf[g][s][kc] = pack8(Wp + (size_t)((g << 7) + ca) * 128 + (kc << 5) + (l4 << 3));
    }
  }
  // Biases: 4 consecutive channels per lane (c = wv*16 + l4*4 + 0..3).
  const int cb = (wv << 4) + (l4 << 2);
  f32x4 br4, bz4, bnx4, bnh4;
  {
    float4 a = *(const float4*)(bih + cb), b2 = *(const float4*)(bhh + cb);
    br4[0] = a.x + b2.x; br4[1] = a.y + b2.y; br4[2] = a.z + b2.z; br4[3] = a.w + b2.w;
    a = *(const float4*)(bih + 128 + cb); b2 = *(const float4*)(bhh + 128 + cb);
    bz4[0] = a.x + b2.x; bz4[1] = a.y + b2.y; bz4[2] = a.z + b2.z; bz4[3] = a.w + b2.w;
    a = *(const float4*)(bih + 256 + cb);
    bnx4[0] = a.x; bnx4[1] = a.y; bnx4[2] = a.z; bnx4[3] = a.w;
    b2 = *(const float4*)(bhh + 256 + cb);
    bnh4[0] = b2.x; bnh4[1] = b2.y; bnh4[2] = b2.z; bnh4[3] = b2.w;
  }

  // zero hbuf[0] (@8192, 4KB)
  *(unsigned long long*)(lds + 8192 + tid * 8) = 0ull;
  f32x4 hst = {0.f, 0.f, 0.f, 0.f};

  // Staging geometry: threads 0..255 each own (row ss = tid>>4, 16B chunk ck).
  const int ss = tid >> 4, ck = tid & 15;
  const unsigned char* xsp =
      (const unsigned char*)xn +
      (vert ? ((size_t)b << 20) + (size_t)(r0 + ss) * 256 + (ck << 4)
            : ((size_t)(b * 64 + r0 + ss) << 14) + (ck << 4));
  const int xstep = vert ? 16384 : 256;
  const int sdst = (ss * 256 + (ck << 4)) ^ ((ss & 15) << 4);

  // Per-lane cat store pointer.
  const int seq = r0 + l15;
  unsigned char* catp =
      (unsigned char*)cat +
      ((size_t)b * 4096 + (size_t)(vert ? seq : seq * 64)) * 1024 + dir * 256 + (cb << 1);
  const int cstep = vert ? 65536 : 1024;

  // Prologue: stage x(t(0)) into xbuf0; preload x(t(1)) into xgB.
  uint4 xgA, xgB;
  if (tid < 256) {
    uint4 v = *(const uint4*)(xsp + (fwd ? 0 : 63) * xstep);
    *(uint4*)(lds + sdst) = v;
    xgB = *(const uint4*)(xsp + (fwd ? 1 : 62) * xstep);
  }
  __syncthreads();

  // One step. XW = staging reg holding x(t+1) (written to xbuf[NXTO]);
  // XL = staging reg receiving x(t+2).
#define STEP(TT, CURO, NXTO, XW, XL)                                            \
  {                                                                             \
    const int t = fwd ? (TT) : 63 - (TT);                                       \
    /* B-fragment reads first (consumed by MFMAs ASAP) */                       \
    bf16x8 ha[4], xa[4];                                                        \
    _Pragma("unroll")                                                           \
    for (int kc = 0; kc < 4; ++kc) {                                            \
      const int base = (l15 * 256 + (kc << 6) + (l4 << 4)) ^ (l15 << 4);        \
      xa[kc] = *(const bf16x8*)(lds + (CURO) + base);                           \
      ha[kc] = *(const bf16x8*)(lds + 8192 + (CURO) + base);                    \
    }                                                                           \
    /* stage x(t+1) (arrived last step) and issue load of x(t+2) */             \
    if (tid < 256) {                                                            \
      *(uint4*)(lds + (NXTO) + sdst) = XW;                                      \
      const int tl = (TT) + 2 > 63 ? 63 : (TT) + 2;                             \
      XL = *(const uint4*)(xsp + (fwd ? tl : 63 - tl) * xstep);                 \
    }                                                                           \
    /* six independent depth-4 MFMA chains */                                   \
    f32x4 rx = br4, zx = bz4, nx = bnx4;                                        \
    f32x4 rh = {0.f, 0.f, 0.f, 0.f}, zh = {0.f, 0.f, 0.f, 0.f}, nh = bnh4;     \
    _Pragma("unroll")                                                           \
    for (int kc = 0; kc < 4; ++kc) {                                            \
      rx = __builtin_amdgcn_mfma_f32_16x16x32_bf16(wf[0][0][kc], xa[kc], rx, 0, 0, 0); \
      rh = __builtin_amdgcn_mfma_f32_16x16x32_bf16(wf[0][1][kc], ha[kc], rh, 0, 0, 0); \
      zx = __builtin_amdgcn_mfma_f32_16x16x32_bf16(wf[1][0][kc], xa[kc], zx, 0, 0, 0); \
      zh = __builtin_amdgcn_mfma_f32_16x16x32_bf16(wf[1][1][kc], ha[kc], zh, 0, 0, 0); \
      nx = __builtin_amdgcn_mfma_f32_16x16x32_bf16(wf[2][0][kc], xa[kc], nx, 0, 0, 0); \
      nh = __builtin_amdgcn_mfma_f32_16x16x32_bf16(wf[2][1][kc], ha[kc], nh, 0, 0, 0); \
    }                                                                           \
    f32x4 hnew;                                                                 \
    _Pragma("unroll")                                                           \
    for (int r = 0; r < 4; ++r) {                                               \
      const float rr = __builtin_amdgcn_rcpf(1.f + __expf(-(rx[r] + rh[r])));   \
      const float zz = __builtin_amdgcn_rcpf(1.f + __expf(-(zx[r] + zh[r])));   \
      const float pre = nx[r] + rr * nh[r];                                     \
      const float e2 = __expf(-2.f * pre);                                      \
      const float nn = fmaf(2.f, __builtin_amdgcn_rcpf(1.f + e2), -1.f);        \
      hnew[r] = nn + zz * (hst[r] - nn);                                        \
    }                                                                           \
    hst = hnew;                                                                 \
    unsigned hp0, hp1;                                                          \
    asm("v_cvt_pk_bf16_f32 %0, %1, %2" : "=v"(hp0) : "v"(hnew[0]), "v"(hnew[1])); \
    asm("v_cvt_pk_bf16_f32 %0, %1, %2" : "=v"(hp1) : "v"(hnew[2]), "v"(hnew[3])); \
    /* h' -> hbuf[NXTO]: row = seq l15, byte col = cb*2, one b64 */             \
    {                                                                           \
      unsigned long long hp = (unsigned long long)hp0 | ((unsigned long long)hp1 << 32); \
      *(unsigned long long*)(lds + 8192 + (NXTO) +                              \
                             ((l15 * 256 + (cb << 1)) ^ (l15 << 4))) = hp;      \
    }                                                                           \
    /* cat store from registers (never drained in-loop) */                      \
    {                                                                           \
      uint2 v; v.x = hp0; v.y = hp1;                                            \
      *(uint2*)(catp + t * cstep) = v;                                          \
    }                                                                           \
    asm volatile("s_waitcnt lgkmcnt(0)" ::: "memory");                          \
    __builtin_amdgcn_s_barrier();                                               \
    asm volatile("" ::: "memory");                                              \
  }

  for (int tt2 = 0; tt2 < 64; tt2 += 2) {
    STEP(tt2, 0, 4096, xgB, xgA);
    STEP(tt2 + 1, 4096, 0, xgA, xgB);
  }
#undef STEP
}

// ---------------- Projection: out = cat[65536,512] @ pw^T + pb + x, -> [B,C,HW] ----------------
__global__ __launch_bounds__(256, 2) void proj_kernel(
    const unsigned short* __restrict__ cat, const float* __restrict__ pw,
    const float* __restrict__ pb, const float* __restrict__ x,
    float* __restrict__ out) {
  __shared__ __align__(16) unsigned char at[65536];
  const int tid = threadIdx.x;
  const int bid = blockIdx.x;
  const int row0 = bid << 6;
  const int b = row0 >> 12;
  const int hw0 = row0 & 4095;
  const int wv = tid >> 6, lane = tid & 63, l15 = lane & 15, l4 = lane >> 4;

#pragma unroll
  for (int it = 0; it < 16; ++it) {
    const int item = tid + (it << 8);
    const int rr = item >> 6, ckk = item & 63;
    uint4 v = *(const uint4*)((const unsigned char*)cat +
                              ((size_t)(row0 + rr)) * 1024 + ckk * 16);
    *(uint4*)(at + rr * 1024 + ((ckk ^ (rr & 7)) << 4)) = v;
  }

  bf16x8 wfr[2][16];
  float pbv[2];
#pragma unroll
  for (int ct = 0; ct < 2; ++ct) {
    const int cc = (wv << 5) + (ct << 4) + l15;
    pbv[ct] = pb[cc];
#pragma unroll
    for (int kc = 0; kc < 16; ++kc)
      wfr[ct][kc] = pack8(pw + (size_t)cc * 512 + (kc << 5) + (l4 << 3));
  }
  __syncthreads();

  f32x4 acc[4][2];
#pragma unroll
  for (int mt = 0; mt < 4; ++mt) {
    acc[mt][0] = {pbv[0], pbv[0], pbv[0], pbv[0]};
    acc[mt][1] = {pbv[1], pbv[1], pbv[1], pbv[1]};
  }
#pragma unroll
  for (int mt = 0; mt < 4; ++mt) {
    const int rr = (mt << 4) + l15;
#pragma unroll
    for (int kc = 0; kc < 16; ++kc) {
      bf16x8 af =
          *(const bf16x8*)(at + rr * 1024 + ((((kc << 2) + l4) ^ (rr & 7)) << 4));
      acc[mt][0] = __builtin_amdgcn_mfma_f32_16x16x32_bf16(af, wfr[0][kc], acc[mt][0], 0, 0, 0);
      acc[mt][1] = __builtin_amdgcn_mfma_f32_16x16x32_bf16(af, wfr[1][kc], acc[mt][1], 0, 0, 0);
    }
  }

#pragma unroll
  for (int mt = 0; mt < 4; ++mt) {
#pragma unroll
    for (int ct = 0; ct < 2; ++ct) {
      const int cc = (wv << 5) + (ct << 4) + l15;
      const int hwb = hw0 + (mt << 4) + (l4 << 2);
      const size_t off = (size_t)(b * 128 + cc) * 4096 + hwb;
      float4 xv = *(const float4*)(x + off);
      float4 o;
      o.x = acc[mt][ct][0] + xv.x;
      o.y = acc[mt][ct][1] + xv.y;
      o.z = acc[mt][ct][2] + xv.z;
      o.w = acc[mt][ct][3] + xv.w;
      *(float4*)(out + off) = o;
    }
  }
}

extern "C" void kernel_launch(void* const* d_in, const int* in_sizes, int n_in,
                              void* d_out, int out_size, void* d_ws, size_t ws_size,
                              hipStream_t stream) {
  const float* x = (const float*)d_in[0];
  const float* lg = (const float*)d_in[1];
  const float* lb = (const float*)d_in[2];
  unsigned short* xn = (unsigned short*)d_ws;  // [16][64][64][128] bf16 = 16.8MB
  unsigned short* cat =
      (unsigned short*)((unsigned char*)d_ws + (size_t)16 * 64 * 64 * 128 * 2);  // [65536][512] bf16 = 67MB

  ln_kernel<<<1024, 256, 0, stream>>>(x, lg, lb, xn);
  scan_kernel<<<256, 512, 0, stream>>>(
      xn, cat,
      (const float*)d_in[3], (const float*)d_in[4], (const float*)d_in[5], (const float*)d_in[6],
      (const float*)d_in[7], (const float*)d_in[8], (const float*)d_in[9], (const float*)d_in[10],
      (const float*)d_in[11], (const float*)d_in[12], (const float*)d_in[13], (const float*)d_in[14],
      (const float*)d_in[15], (const float*)d_in[16], (const float*)d_in[17], (const float*)d_in[18]);
  proj_kernel<<<1024, 256, 0, stream>>>(cat, (const float*)d_in[19], (const float*)d_in[20], x,
                                        (float*)d_out);
}